// Round 14
// baseline (56.546 us; speedup 1.0000x reference)
//
#include <hip/hip_runtime.h>

#define HH 56
#define WW 56
#define HWSZ 3136
#define KS 7
#define KK 49

#define XS3 136   // ka xls stride in shorts: 16px*8c + 8 pad
#define TBS 72    // ka tbuf stride in shorts

typedef __attribute__((ext_vector_type(8))) short short8;
typedef __attribute__((ext_vector_type(4))) float f32x4;

__device__ inline unsigned short f2bf(float f) {
    unsigned u = __builtin_bit_cast(unsigned, f);
    u += 0x7FFF + ((u >> 16) & 1);          // RNE
    return (unsigned short)(u >> 16);
}
__device__ inline unsigned pk2(float a, float b) {   // RNE pack
    return (unsigned)f2bf(a) | ((unsigned)f2bf(b) << 16);
}
__device__ inline unsigned pktr(float lo, float hi) { // truncation pack, 1 v_perm
    return __builtin_amdgcn_perm(__builtin_bit_cast(unsigned, hi),
                                 __builtin_bit_cast(unsigned, lo), 0x07060302u);
}
__device__ inline float bflo(unsigned u) { return __builtin_bit_cast(float, u << 16); }
__device__ inline float bfhi(unsigned u) { return __builtin_bit_cast(float, u & 0xFFFF0000u); }

// ---- ka16: t[p][64] = relu(BN(x @ w1^T)) bf16; blocks 0..783 = 16-px tiles,
//      blocks 784..799 = w2->bf16 prep (kb-only data, safe to fold).
//      LAUNCHED TWICE for attribution (idempotent).
__global__ __launch_bounds__(256) void ka16(
    const float* __restrict__ x, const float* __restrict__ w1,
    const float* __restrict__ gamma, const float* __restrict__ beta,
    const float* __restrict__ mean, const float* __restrict__ var,
    const float* __restrict__ w2,
    unsigned short* __restrict__ t_bf, unsigned short* __restrict__ w2p)
{
    const int tid = threadIdx.x;
    if (blockIdx.x >= 784) {
        const int g = blockIdx.x - 784;
        #pragma unroll
        for (int it = 0; it < 16; ++it) {
            const int i = it * 256 + tid;
            const int r = i >> 6, k = i & 63;
            float v = (r < KK) ? w2[(g * KK + r) * 64 + k] : 0.f;
            w2p[(g * 64 + r) * 64 + k] = f2bf(v);
        }
        return;
    }

    __shared__ __align__(16) unsigned short xls[32 * XS3];   // 8.7 KB
    __shared__ __align__(16) unsigned short tbuf[16 * TBS];  // 2.3 KB

    const int p0 = blockIdx.x * 16;          // 3136 % 16 == 0: never crosses b
    const int b = p0 / HWSZ, hw0 = p0 - b * HWSZ;

    // stage x[16px][256c] -> bf16 LDS, coalesced float4 reads, 4 loads batched
    {
        const int quad = tid & 3, cs = tid >> 2;            // px-quad, c-slot
        const int base = b * 256 * HWSZ + hw0 + quad * 4;
        const int off0 = (cs * 2) * HWSZ + base;
        const int off1 = ((cs + 64) * 2) * HWSZ + base;
        float4 va0 = *(const float4*)(x + off0);
        float4 vb0 = *(const float4*)(x + off0 + HWSZ);
        float4 va1 = *(const float4*)(x + off1);
        float4 vb1 = *(const float4*)(x + off1 + HWSZ);
        unsigned short* wp0 = xls + (cs >> 2) * XS3 + quad * 32 + (cs & 3) * 2;
        unsigned short* wp1 = wp0 + 16 * XS3;
        *(unsigned*)(wp0 + 0)  = pktr(va0.x, vb0.x);
        *(unsigned*)(wp0 + 8)  = pktr(va0.y, vb0.y);
        *(unsigned*)(wp0 + 16) = pktr(va0.z, vb0.z);
        *(unsigned*)(wp0 + 24) = pktr(va0.w, vb0.w);
        *(unsigned*)(wp1 + 0)  = pktr(va1.x, vb1.x);
        *(unsigned*)(wp1 + 8)  = pktr(va1.y, vb1.y);
        *(unsigned*)(wp1 + 16) = pktr(va1.z, vb1.z);
        *(unsigned*)(wp1 + 24) = pktr(va1.w, vb1.w);
    }

    const int lane = tid & 63, wv = tid >> 6;
    const int m = lane & 15, q = lane >> 4;

    // A-fragments straight from w1 f32 (L2-hot), trunc pack
    short8 af[8];
    {
        const int woff = (wv * 16 + m) * 256 + q * 8;
        #pragma unroll
        for (int ks = 0; ks < 8; ++ks) {
            float4 f0 = *(const float4*)(w1 + woff + ks * 32);
            float4 f1 = *(const float4*)(w1 + woff + ks * 32 + 4);
            uint4 u = make_uint4(pktr(f0.x, f0.y), pktr(f0.z, f0.w),
                                 pktr(f1.x, f1.y), pktr(f1.z, f1.w));
            af[ks] = __builtin_bit_cast(short8, u);
        }
    }
    __syncthreads();

    // GEMM1: wave wv owns o-tile; single 16-px n-tile
    f32x4 acc = {0.f, 0.f, 0.f, 0.f};
    #pragma unroll
    for (int ks = 0; ks < 8; ++ks) {
        short8 bfr = *(const short8*)&xls[(ks * 4 + q) * XS3 + m * 8];
        acc = __builtin_amdgcn_mfma_f32_16x16x32_bf16(af[ks], bfr, acc, 0, 0, 0);
    }
    // D: col(lane&15)=px, row((lane>>4)*4+j)=o — verified layout
    {
        const int ob = wv * 16 + q * 4;
        float4 g4 = *(const float4*)&gamma[ob];
        float4 v4 = *(const float4*)&var[ob];
        float4 m4 = *(const float4*)&mean[ob];
        float4 b4 = *(const float4*)&beta[ob];
        float gg[4] = {g4.x, g4.y, g4.z, g4.w};
        float vv[4] = {v4.x, v4.y, v4.z, v4.w};
        float mm[4] = {m4.x, m4.y, m4.z, m4.w};
        float bb[4] = {b4.x, b4.y, b4.z, b4.w};
        float r[4];
        #pragma unroll
        for (int j = 0; j < 4; ++j) {
            float sc = gg[j] * rsqrtf(vv[j] + 1e-5f);
            float sh = bb[j] - mm[j] * sc;
            float val = acc[j] * sc + sh;
            r[j] = val > 0.f ? val : 0.f;
        }
        *(uint2*)&tbuf[m * TBS + ob] = make_uint2(pk2(r[0], r[1]), pk2(r[2], r[3]));
    }
    __syncthreads();

    // coalesced t store: 128 threads x uint4
    if (tid < 128) {
        const int px = tid >> 3, seg = tid & 7;
        uint4 v = *(const uint4*)&tbuf[px * TBS + seg * 8];
        *(uint4*)&t_bf[(p0 + px) * 64 + seg * 8] = v;
    }
}

// ---- kb: GEMM2 (1 group) + pipelined dynamic conv; grid 3584, chunked swizzle ----
__global__ __launch_bounds__(256) void kb(
    const float* __restrict__ y, const float* __restrict__ b2,
    const unsigned short* __restrict__ t_bf, const unsigned short* __restrict__ w2p,
    float* __restrict__ out)
{
    __shared__ __align__(16) unsigned short wgt[52 * 68];   // 7 KB

    const int tid = threadIdx.x;
    const int lin = (blockIdx.x & 7) * 448 + (blockIdx.x >> 3);  // 0..3583
    const int bh = lin >> 4, g = lin & 15;   // contiguous bh per XCD
    const int b = bh / HH, h = bh - b * HH;
    const int p0 = b * HWSZ + h * WW;

    const int lane = tid & 63, wv = tid >> 6;
    const int m = lane & 15, q = lane >> 4;

    // GEMM2: wave = pixel-tile; t from global (L2-hot); B-frags hoisted
    {
        const unsigned short* ta = t_bf + (p0 + wv * 16 + m) * 64 + q * 8;
        short8 a0 = *(const short8*)ta;
        short8 a1 = *(const short8*)(ta + 32);
        short8 bfr[8];
        #pragma unroll
        for (int mt = 0; mt < 4; ++mt) {
            const int tboff = (g * 64 + mt * 16 + m) * 64 + q * 8;
            bfr[mt * 2]     = *(const short8*)(w2p + tboff);
            bfr[mt * 2 + 1] = *(const short8*)(w2p + tboff + 32);
        }
        f32x4 acc[4];
        #pragma unroll
        for (int mt = 0; mt < 4; ++mt) { acc[mt][0]=0.f; acc[mt][1]=0.f; acc[mt][2]=0.f; acc[mt][3]=0.f; }
        #pragma unroll
        for (int mt = 0; mt < 4; ++mt) {
            acc[mt] = __builtin_amdgcn_mfma_f32_16x16x32_bf16(a0, bfr[mt * 2],     acc[mt], 0, 0, 0);
            acc[mt] = __builtin_amdgcn_mfma_f32_16x16x32_bf16(a1, bfr[mt * 2 + 1], acc[mt], 0, 0, 0);
        }
        // D: col(kk)=lane&15, row(px)=(lane>>4)*4+j — verified layout
        #pragma unroll
        for (int mt = 0; mt < 4; ++mt) {
            const int kk = mt * 16 + m;
            if (kk < 52) {
                float bv = (kk < KK) ? b2[g * KK + kk] : 0.f;
                f32x4 v = acc[mt];
                *(uint2*)&wgt[kk * 68 + wv * 16 + q * 4] =
                    make_uint2(pk2(v[0] + bv, v[1] + bv), pk2(v[2] + bv, v[3] + bv));
            }
        }
    }
    __syncthreads();

    // conv: 1cc x 4px per thread, 1-row-deep pipelined loads
    if (tid < 224) {
        const int cc = tid / 14, pq = tid - cc * 14;
        const unsigned short* wg = &wgt[pq * 4];
        const bool eL = (pq > 0), eR = (pq < 13);
        const int offL = eL ? 0 : 4;
        const int offR = eR ? 8 : 4;
        const float* ybase = y + (size_t)b * 256 * HWSZ;
        const int yoff = (g * 16 + cc) * HWSZ + pq * 4 - 4;

        float4 cA0, cA1, cA2, nA0, nA1, nA2;
        {
            const int hs = h - 3;
            const int hsc = hs < 0 ? 0 : hs;
            const int r0 = yoff + hsc * WW;
            cA0 = *(const float4*)(ybase + r0 + offL);
            cA1 = *(const float4*)(ybase + r0 + 4);
            cA2 = *(const float4*)(ybase + r0 + offR);
        }
        float a00 = 0.f, a01 = 0.f, a02 = 0.f, a03 = 0.f;

        #pragma unroll
        for (int di = 0; di < KS; ++di) {
            if (di < 6) {
                const int hs = h - 2 + di;
                const int hsc = hs < 0 ? 0 : (hs > HH - 1 ? HH - 1 : hs);
                const int r0 = yoff + hsc * WW;
                nA0 = *(const float4*)(ybase + r0 + offL);
                nA1 = *(const float4*)(ybase + r0 + 4);
                nA2 = *(const float4*)(ybase + r0 + offR);
            }
            const int hs = h - 3 + di;
            if ((unsigned)hs < HH) {
                float w0[11];
                w0[1] = eL ? cA0.y : 0.f;  w0[2] = eL ? cA0.z : 0.f;  w0[3] = eL ? cA0.w : 0.f;
                w0[4] = cA1.x; w0[5] = cA1.y; w0[6] = cA1.z; w0[7] = cA1.w;
                w0[8] = eR ? cA2.x : 0.f;  w0[9] = eR ? cA2.y : 0.f;  w0[10] = eR ? cA2.z : 0.f;
                #pragma unroll
                for (int dj = 0; dj < KS; ++dj) {
                    uint2 wr = *(const uint2*)&wg[(di * KS + dj) * 68];
                    a00 += bflo(wr.x) * w0[dj + 1];
                    a01 += bfhi(wr.x) * w0[dj + 2];
                    a02 += bflo(wr.y) * w0[dj + 3];
                    a03 += bfhi(wr.y) * w0[dj + 4];
                }
            }
            if (di < 6) { cA0 = nA0; cA1 = nA1; cA2 = nA2; }
        }
        float* o0 = out + (size_t)(b * 256 + g * 16 + cc) * HWSZ + h * WW + pq * 4;
        *(float4*)o0 = make_float4(a00, a01, a02, a03);
    }
}

extern "C" void kernel_launch(void* const* d_in, const int* in_sizes, int n_in,
                              void* d_out, int out_size, void* d_ws, size_t ws_size,
                              hipStream_t stream) {
    const float* x     = (const float*)d_in[0];
    const float* y     = (const float*)d_in[1];
    const float* w1    = (const float*)d_in[2];
    const float* gamma = (const float*)d_in[3];
    const float* beta  = (const float*)d_in[4];
    const float* mean  = (const float*)d_in[5];
    const float* var   = (const float*)d_in[6];
    const float* w2    = (const float*)d_in[7];
    const float* b2    = (const float*)d_in[8];
    float* out = (float*)d_out;

    unsigned short* t_bf = (unsigned short*)d_ws;        // [12608][64] bf16 (pad rows)
    unsigned short* w2p  = t_bf + 12608 * 64;            // [16*64][64] bf16

    // ka16 launched TWICE (idempotent) — attribution: delta vs r13 isolates ka16's true cost
    ka16<<<800, 256, 0, stream>>>(x, w1, gamma, beta, mean, var, w2, t_bf, w2p);
    ka16<<<800, 256, 0, stream>>>(x, w1, gamma, beta, mean, var, w2, t_bf, w2p);
    kb  <<<3584, 256, 0, stream>>>(y, b2, t_bf, w2p, out);
}